// Round 14
// baseline (1169.019 us; speedup 1.0000x reference)
//
#include <hip/hip_runtime.h>

#define T_STEPS 1024
#define B_TOT   512
#define VOCAB   1000
#define EMB     64
#define HID     64
#define GATES   256   // 4*HID

typedef float f4 __attribute__((ext_vector_type(4)));
typedef float f2 __attribute__((ext_vector_type(2)));

__device__ __forceinline__ float fast_rcp(float x)  { return __builtin_amdgcn_rcpf(x); }
__device__ __forceinline__ float fast_exp2(float x) { return __builtin_amdgcn_exp2f(x); }

__device__ __forceinline__ float sigmoid_f(float x) {
    return fast_rcp(1.0f + fast_exp2(-1.4426950408889634f * x));
}
__device__ __forceinline__ float tanh_f(float x) {
    float e = fast_exp2(2.8853900817779268f * x);
    return 1.0f - 2.0f * fast_rcp(e + 1.0f);
}

// ---------------------------------------------------------------------------
// Kernel 1: zx table. Layout [dir][vocab][wave][unit][pair]:
//   thread j (0..255): p=j&1, u=(j>>1)&63, w=j>>7, source col=(2w+p)*64+u.
// Recurrent lane (w,u) gathers float2 index tok*128 + w*64 + u
//   = (z_gate(2w), z_gate(2w+1)) with bias and x-projection folded in.
// ---------------------------------------------------------------------------
__global__ __launch_bounds__(256, 4)
void zx_table_kernel(const float* __restrict__ emb,
                     const float* __restrict__ Wx_f, const float* __restrict__ b_f,
                     const float* __restrict__ Wx_b, const float* __restrict__ b_b,
                     float* __restrict__ zx_tab)
{
    const int bid = blockIdx.x;            // 0..1999
    const int dir = bid / VOCAB;
    const int v   = bid - dir * VOCAB;
    const int j   = threadIdx.x;
    const int p   = j & 1;
    const int u   = (j >> 1) & 63;
    const int w   = j >> 7;
    const int col = (2 * w + p) * HID + u;

    const float* __restrict__ Wx = dir ? Wx_b : Wx_f;
    const float* __restrict__ bv = dir ? b_b  : b_f;

    __shared__ float4 x4[EMB / 4];
    if (j < EMB / 4) x4[j] = ((const float4*)emb)[v * (EMB / 4) + j];
    __syncthreads();

    float a0 = bv[col], a1 = 0.f, a2 = 0.f, a3 = 0.f;
#pragma unroll
    for (int q = 0; q < EMB / 4; ++q) {
        float4 xv = x4[q];
        a0 = fmaf(xv.x, Wx[(4 * q + 0) * GATES + col], a0);
        a1 = fmaf(xv.y, Wx[(4 * q + 1) * GATES + col], a1);
        a2 = fmaf(xv.z, Wx[(4 * q + 2) * GATES + col], a2);
        a3 = fmaf(xv.w, Wx[(4 * q + 3) * GATES + col], a3);
    }
    zx_tab[(dir * VOCAB + v) * GATES + j] = (a0 + a1) + (a2 + a3);
}

// ---------------------------------------------------------------------------
// Kernel 2: recurrence, fp32, TWO PHASE-OFFSET CHAINS per block.
// Block = 128 thr = 2 gate-split waves (w0: gates i,f; w1: g,o), handling
// rows A and B of the same dir, phase-shifted by half an iteration:
//   Region1: A-dot(t) | A-act | w1 publishes A{g,o} | w1 does B-update(t-1)
//   barrier
//   Region2: B-dot(t) | B-act | w0 publishes B{i,f} | w0 does A-update(t)
//   barrier
// Each region's 128-fmaf dot statically fills the OTHER chain's exchange /
// transcendental / LDS latency — the stall window that R4's barrier-coupled
// waves exposed. One barrier per chain-step. All LDS buffers single
// (write/read pairs are always separated by a barrier). Updates alternate
// waves, so per-iteration load is balanced.
// ---------------------------------------------------------------------------
__global__ __launch_bounds__(128, 2)
void lstm_rec_kernel(const int* __restrict__ tokens,
                     const float* __restrict__ Wh_f,
                     const float* __restrict__ Wh_b,
                     const float* __restrict__ zx_tab,
                     float* __restrict__ out)
{
    const int bx   = blockIdx.x;        // 0..511
    const int dir  = bx >> 8;
    const int rp   = bx & 255;
    const int rowA = rp * 2, rowB = rp * 2 + 1;
    const int u    = threadIdx.x & 63;  // hidden unit
    const int w    = threadIdx.x >> 6;  // 0: gates i,f ; 1: gates g,o

    const float* __restrict__ Wh  = dir ? Wh_b : Wh_f;
    const f2*    __restrict__ zx2 = (const f2*)(zx_tab + dir * (VOCAB * GATES));
    const int*   __restrict__ trA = tokens + rowA * T_STEPS;
    const int*   __restrict__ trB = tokens + rowB * T_STEPS;

    // 128 register-resident fp32 weights (shared by both chains - same dir).
    const int colE = (2 * w) * HID + u;
    const int colO = colE + HID;
    float whE[HID], whO[HID];
#pragma unroll
    for (int k = 0; k < HID; ++k) whE[k] = Wh[k * GATES + colE];
#pragma unroll
    for (int k = 0; k < HID; ++k) whO[k] = Wh[k * GATES + colO];

    __shared__ float hA[HID], hB[HID];  // hidden states (single-buffered)
    __shared__ f2 actAgo[HID];          // w1 -> w0: A's {g,o} acts
    __shared__ f2 actBif[HID];          // w0 -> w1: B's {i,f} acts

    if (threadIdx.x < HID) hA[threadIdx.x] = 0.0f;
    else                   hB[threadIdx.x - HID] = 0.0f;

    float cA = 0.f, cB = 0.f;           // cA lives on w0 lanes, cB on w1
    float hAv = 0.f, hBv = 0.f;         // carried h outputs
    float aAe = 0.f, aAo = 0.f;         // own A-acts (region1 -> region2)
    float aBe = 0.f, aBo = 0.f;         // own B-acts (region2 -> next region1)

#define POS(t) (dir ? (T_STEPS - 1 - (t)) : (t))
    int tAc = trA[POS(0)], tAn = trA[POS(1)];
    int tBc = trB[POS(0)], tBn = trB[POS(1)];
    int tBp = 0;                        // tokB(t-1)
    f2 zxAc = zx2[tAc * 128 + w * 64 + u];
    f2 zxBc = zx2[tBc * 128 + w * 64 + u];

    const f4* __restrict__ hA4 = (const f4*)hA;
    const f4* __restrict__ hB4 = (const f4*)hB;

    __syncthreads();

#pragma unroll 1
    for (int t = 0; t < T_STEPS; ++t) {
        const int sp = POS((t + 2 < T_STEPS) ? (t + 2) : (T_STEPS - 1));

        // ========== REGION 1: A-dot(t)  +  B-update(t-1) ==========
        int tAf = trA[sp];                      // prefetch tokens A(t+2)
        f2  zxAn = zx2[tAn * 128 + w * 64 + u]; // prefetch zx A(t+1)

        float e0 = zxAc.x, e1 = 0.f, e2 = 0.f, e3 = 0.f;
        float o0 = zxAc.y, o1 = 0.f, o2 = 0.f, o3 = 0.f;
#pragma unroll
        for (int q = 0; q < HID / 4; ++q) {
            f4 hv = hA4[q];                     // uniform LDS broadcast
            e0 = fmaf(hv.x, whE[4 * q + 0], e0);
            e1 = fmaf(hv.y, whE[4 * q + 1], e1);
            e2 = fmaf(hv.z, whE[4 * q + 2], e2);
            e3 = fmaf(hv.w, whE[4 * q + 3], e3);
            o0 = fmaf(hv.x, whO[4 * q + 0], o0);
            o1 = fmaf(hv.y, whO[4 * q + 1], o1);
            o2 = fmaf(hv.z, whO[4 * q + 2], o2);
            o3 = fmaf(hv.w, whO[4 * q + 3], o3);
        }
        float zAe = (e0 + e1) + (e2 + e3);
        float zAo = (o0 + o1) + (o2 + o3);

        if (w == 0) {                           // i, f (keep in regs)
            aAe = sigmoid_f(zAe);
            aAo = sigmoid_f(zAo);
        } else {                                // g, o (publish for w0)
            aAe = tanh_f(zAe);
            aAo = sigmoid_f(zAo);
            f2 v; v.x = aAe; v.y = aAo;
            actAgo[u] = v;
            if (t > 0) {                        // B-update(t-1) on w1
                f2 bif = actBif[u];             // B{i,f} from region2(t-1)
                if (tBp != 0) {                 // Keras mask_zero carry
                    cB  = fmaf(bif.y, cB, bif.x * aBe);   // f*c + i*g
                    hBv = aBo * tanh_f(cB);
                }
                hB[u] = hBv;
            }
        }
        __syncthreads();                        // bar1

        // ========== REGION 2: B-dot(t)  +  A-update(t) ==========
        int tBf = trB[sp];                      // prefetch tokens B(t+2)
        f2  zxBn = zx2[tBn * 128 + w * 64 + u]; // prefetch zx B(t+1)

        e0 = zxBc.x; e1 = 0.f; e2 = 0.f; e3 = 0.f;
        o0 = zxBc.y; o1 = 0.f; o2 = 0.f; o3 = 0.f;
#pragma unroll
        for (int q = 0; q < HID / 4; ++q) {
            f4 hv = hB4[q];
            e0 = fmaf(hv.x, whE[4 * q + 0], e0);
            e1 = fmaf(hv.y, whE[4 * q + 1], e1);
            e2 = fmaf(hv.z, whE[4 * q + 2], e2);
            e3 = fmaf(hv.w, whE[4 * q + 3], e3);
            o0 = fmaf(hv.x, whO[4 * q + 0], o0);
            o1 = fmaf(hv.y, whO[4 * q + 1], o1);
            o2 = fmaf(hv.z, whO[4 * q + 2], o2);
            o3 = fmaf(hv.w, whO[4 * q + 3], o3);
        }
        float zBe = (e0 + e1) + (e2 + e3);
        float zBo = (o0 + o1) + (o2 + o3);

        if (w == 0) {                           // B i, f: publish for w1
            aBe = sigmoid_f(zBe);
            aBo = sigmoid_f(zBo);
            f2 v; v.x = aBe; v.y = aBo;
            actBif[u] = v;
            f2 ago = actAgo[u];                 // A{g,o} from region1(t)
            if (tAc != 0) {                     // A-update(t) on w0
                cA  = fmaf(aAo, cA, aAe * ago.x);
                hAv = ago.y * tanh_f(cA);
            }
            hA[u] = hAv;
        } else {                                // B g, o (keep for region1)
            aBe = tanh_f(zBe);
            aBo = sigmoid_f(zBo);
        }
        __syncthreads();                        // bar2

        tBp = tBc;
        tAc = tAn; tAn = tAf; zxAc = zxAn;
        tBc = tBn; tBn = tBf; zxBc = zxBn;
    }

    // Epilogue: B-update(T-1) still pending on w1.
    if (w == 1) {
        f2 bif = actBif[u];
        if (tBp != 0) {
            cB  = fmaf(bif.y, cB, bif.x * aBe);
            hBv = aBo * tanh_f(cB);
        }
        out[rowB * (2 * HID) + dir * HID + u] = hBv;
    } else {
        out[rowA * (2 * HID) + dir * HID + u] = hAv;
    }
#undef POS
}

extern "C" void kernel_launch(void* const* d_in, const int* in_sizes, int n_in,
                              void* d_out, int out_size, void* d_ws, size_t ws_size,
                              hipStream_t stream) {
    const int*   tokens = (const int*)  d_in[0];
    const float* emb    = (const float*)d_in[1];
    const float* Wx_f   = (const float*)d_in[2];
    const float* Wh_f   = (const float*)d_in[3];
    const float* b_f    = (const float*)d_in[4];
    const float* Wx_b   = (const float*)d_in[5];
    const float* Wh_b   = (const float*)d_in[6];
    const float* b_b    = (const float*)d_in[7];
    float* out = (float*)d_out;

    float* zx_tab = (float*)d_ws;   // 2*1000*256*4 = 1.95 MB of d_ws

    hipLaunchKernelGGL(zx_table_kernel, dim3(2 * VOCAB), dim3(GATES), 0, stream,
                       emb, Wx_f, b_f, Wx_b, b_b, zx_tab);
    hipLaunchKernelGGL(lstm_rec_kernel, dim3(B_TOT), dim3(128), 0, stream,
                       tokens, Wh_f, Wh_b, zx_tab, out);
}

// Round 15
// 595.979 us; speedup vs baseline: 1.9615x; 1.9615x over previous
//
#include <hip/hip_runtime.h>

#define T_STEPS 1024
#define B_TOT   512
#define VOCAB   1000
#define EMB     64
#define HID     64
#define GATES   256   // 4*HID

typedef float f4 __attribute__((ext_vector_type(4)));
typedef float f2 __attribute__((ext_vector_type(2)));

__device__ __forceinline__ float fast_rcp(float x)  { return __builtin_amdgcn_rcpf(x); }
__device__ __forceinline__ float fast_exp2(float x) { return __builtin_amdgcn_exp2f(x); }

__device__ __forceinline__ float sigmoid_f(float x) {
    return fast_rcp(1.0f + fast_exp2(-1.4426950408889634f * x));
}
__device__ __forceinline__ float tanh_f(float x) {
    float e = fast_exp2(2.8853900817779268f * x);
    return 1.0f - 2.0f * fast_rcp(e + 1.0f);
}

// packed fp32 FMA: acc.lo += a.lo*b.lo ; acc.hi += a.hi*b.hi (2 MACs/instr).
// If CDNA4's 157.3 TF fp32 peak is real, this issues at normal VALU rate.
__device__ __forceinline__ void pk_fma_acc(f2& acc, f2 a, f2 b) {
    asm("v_pk_fma_f32 %0, %1, %2, %0" : "+v"(acc) : "v"(a), "v"(b));
}

// ---------------------------------------------------------------------------
// Kernel 1: zx table. Layout [dir][vocab][wave][unit][pair]:
//   thread j (0..255): p=j&1, u=(j>>1)&63, w=j>>7, source col=(2w+p)*64+u.
// Recurrent lane (w,u) gathers float2 index tok*128 + w*64 + u.
// ---------------------------------------------------------------------------
__global__ __launch_bounds__(256, 4)
void zx_table_kernel(const float* __restrict__ emb,
                     const float* __restrict__ Wx_f, const float* __restrict__ b_f,
                     const float* __restrict__ Wx_b, const float* __restrict__ b_b,
                     float* __restrict__ zx_tab)
{
    const int bid = blockIdx.x;            // 0..1999
    const int dir = bid / VOCAB;
    const int v   = bid - dir * VOCAB;
    const int j   = threadIdx.x;
    const int p   = j & 1;
    const int u   = (j >> 1) & 63;
    const int w   = j >> 7;
    const int col = (2 * w + p) * HID + u;

    const float* __restrict__ Wx = dir ? Wx_b : Wx_f;
    const float* __restrict__ bv = dir ? b_b  : b_f;

    __shared__ float4 x4[EMB / 4];
    if (j < EMB / 4) x4[j] = ((const float4*)emb)[v * (EMB / 4) + j];
    __syncthreads();

    float a0 = bv[col], a1 = 0.f, a2 = 0.f, a3 = 0.f;
#pragma unroll
    for (int q = 0; q < EMB / 4; ++q) {
        float4 xv = x4[q];
        a0 = fmaf(xv.x, Wx[(4 * q + 0) * GATES + col], a0);
        a1 = fmaf(xv.y, Wx[(4 * q + 1) * GATES + col], a1);
        a2 = fmaf(xv.z, Wx[(4 * q + 2) * GATES + col], a2);
        a3 = fmaf(xv.w, Wx[(4 * q + 3) * GATES + col], a3);
    }
    zx_tab[(dir * VOCAB + v) * GATES + j] = (a0 + a1) + (a2 + a3);
}

// ---------------------------------------------------------------------------
// Kernel 2: recurrence — R4 structure EXACTLY (best: 626 us), with the dot
// product switched from 128 scalar v_fmac to 64 v_pk_fma_f32 (single
// experimental variable: fp32 packed issue rate).
// Block = 128 thr = 2 waves per (dir,row): 1024 blocks -> 2 waves/SIMD.
//   wave 0, lane u: gates i,f of unit u ; wave 1, lane u: gates g,o.
// Per step: 64 pk_fma/lane (4 packed chains) -> own-gate activations ->
// wave1 writes float2{g,o} -> barrier -> wave0 lane-parallel c/h update,
// writes h -> barrier.
// ---------------------------------------------------------------------------
__global__ __launch_bounds__(128, 2)
void lstm_rec_kernel(const int* __restrict__ tokens,
                     const float* __restrict__ Wh_f,
                     const float* __restrict__ Wh_b,
                     const float* __restrict__ zx_tab,
                     float* __restrict__ out)
{
    const int bx  = blockIdx.x;        // 0..1023
    const int dir = bx >> 9;
    const int row = bx & 511;
    const int u   = threadIdx.x & 63;  // hidden unit
    const int w   = threadIdx.x >> 6;  // wave id: 0 -> gates i,f ; 1 -> g,o

    const float* __restrict__ Wh   = dir ? Wh_b : Wh_f;
    const f2*    __restrict__ zx2  = (const f2*)(zx_tab + dir * (VOCAB * GATES));
    const int*   __restrict__ trow = tokens + row * T_STEPS;

    // 128 register-resident fp32 weights as 64 packed f2 pairs:
    // whA2[m] = (Wh[2m][colA], Wh[2m+1][colA]), same for colB.
    const int colA = (2 * w) * HID + u;
    const int colB = colA + HID;
    f2 whA2[HID / 2], whB2[HID / 2];
#pragma unroll
    for (int m = 0; m < HID / 2; ++m) {
        f2 a; a.x = Wh[(2 * m) * GATES + colA]; a.y = Wh[(2 * m + 1) * GATES + colA];
        whA2[m] = a;
        f2 b; b.x = Wh[(2 * m) * GATES + colB]; b.y = Wh[(2 * m + 1) * GATES + colB];
        whB2[m] = b;
    }

    __shared__ float hbuf[HID];        // h broadcast (fp32)
    __shared__ f2    act2[HID];        // wave1 -> wave0: {g, o}

    if (threadIdx.x < HID) hbuf[threadIdx.x] = 0.0f;
    float c = 0.0f;                    // cell state (wave 0 lanes)
    __syncthreads();

    // wave-uniform token chain + zx prefetch (float2 per lane)
    int tokc = trow[dir ? (T_STEPS - 1) : 0];
    int tokn = trow[dir ? (T_STEPS - 2) : 1];
    f2  zxc  = zx2[tokc * 128 + w * 64 + u];

    const f4* __restrict__ hb4 = (const f4*)hbuf;

#pragma unroll 1
    for (int t = 0; t < T_STEPS; ++t) {
        // prefetches first: latency hides under the pk_fma block
        int t2   = (t + 2 < T_STEPS) ? (t + 2) : (T_STEPS - 1);
        int tokf = trow[dir ? (T_STEPS - 1 - t2) : t2];
        f2  zxn  = zx2[tokn * 128 + w * 64 + u];

        // ---- two 64-dim dots as 64 pk_fma (4 packed chains) ----
        f2 accA0; accA0.x = zxc.x; accA0.y = 0.f;
        f2 accA1; accA1.x = 0.f;   accA1.y = 0.f;
        f2 accB0; accB0.x = zxc.y; accB0.y = 0.f;
        f2 accB1; accB1.x = 0.f;   accB1.y = 0.f;
#pragma unroll
        for (int q = 0; q < HID / 4; ++q) {
            f4 hv = hb4[q];                      // LDS broadcast, conflict-free
            f2 hlo; hlo.x = hv.x; hlo.y = hv.y;
            f2 hhi; hhi.x = hv.z; hhi.y = hv.w;
            pk_fma_acc(accA0, hlo, whA2[2 * q]);
            pk_fma_acc(accA1, hhi, whA2[2 * q + 1]);
            pk_fma_acc(accB0, hlo, whB2[2 * q]);
            pk_fma_acc(accB1, hhi, whB2[2 * q + 1]);
        }
        float zA = (accA0.x + accA1.x) + (accA0.y + accA1.y);
        float zB = (accB0.x + accB1.x) + (accB0.y + accB1.y);

        // ---- own-gate activations (both waves busy, wave-uniform branch) ----
        float actA, actB;
        if (w == 0) {                  // i, f
            actA = sigmoid_f(zA);
            actB = sigmoid_f(zB);
        } else {                       // g, o
            actA = tanh_f(zA);
            actB = sigmoid_f(zB);
            f2 go; go.x = actA; go.y = actB;
            act2[u] = go;
        }
        __syncthreads();

        // ---- state update: wave 0, lane-parallel ----
        if (w == 0 && tokc != 0) {     // Keras mask_zero: carry when padded
            f2 go = act2[u];
            c = fmaf(actB, c, actA * go.x);        // c = f*c + i*g
            hbuf[u] = go.y * tanh_f(c);            // h = o*tanh(c)
        }
        __syncthreads();

        tokc = tokn; tokn = tokf; zxc = zxn;
    }

    if (w == 0)
        out[row * (2 * HID) + dir * HID + u] = hbuf[u];
}

extern "C" void kernel_launch(void* const* d_in, const int* in_sizes, int n_in,
                              void* d_out, int out_size, void* d_ws, size_t ws_size,
                              hipStream_t stream) {
    const int*   tokens = (const int*)  d_in[0];
    const float* emb    = (const float*)d_in[1];
    const float* Wx_f   = (const float*)d_in[2];
    const float* Wh_f   = (const float*)d_in[3];
    const float* b_f    = (const float*)d_in[4];
    const float* Wx_b   = (const float*)d_in[5];
    const float* Wh_b   = (const float*)d_in[6];
    const float* b_b    = (const float*)d_in[7];
    float* out = (float*)d_out;

    float* zx_tab = (float*)d_ws;   // 2*1000*256*4 = 1.95 MB of d_ws

    hipLaunchKernelGGL(zx_table_kernel, dim3(2 * VOCAB), dim3(GATES), 0, stream,
                       emb, Wx_f, b_f, Wx_b, b_b, zx_tab);
    hipLaunchKernelGGL(lstm_rec_kernel, dim3(2 * B_TOT), dim3(128), 0, stream,
                       tokens, Wh_f, Wh_b, zx_tab, out);
}